// Round 7
// baseline (365.635 us; speedup 1.0000x reference)
//
#include <hip/hip_runtime.h>

// ToDenseBEVConvolution R18 — 4 nodes, all kernels minimal.
// Ledger: R11 (5n, 351.3) best; R15 (4n, 357.8) = saved a boundary (-12) but
// paid ~+18us in K2's prologue (psum+scan+binsearch in all 1266 blocks);
// R16 walk-in-dense +20us (twice measured); R17 o16-dense +7us (f already
// cache-resident -> dense at store floor). R18 removes R15's prologue
// entirely: point blocks re-indexed as (bin, sort-block-PAIR) so each block
// finds its points with TWO blkhist loads (rank rr -> vb0 if rr<c0 else
// vb1) — no scan, no search, no atomics, no gcnt, no memset node.
//  K1 bev_sort:  zero head inline + per-block histograms (blkhist) +
//                block-segmented sorted (R15 verbatim).
//  K2 bev_point: block (bin,pair): c=c0+c1 (~32 avg) points, batch loop for
//                Poisson tails; LDS-kernel matmul + chain push (proven body).
//  K3 bev_accum: owner folds collision chain in-place (R11 D4 verbatim).
//  K4 bev_dense_row: branch-free wave-per-row dense (R11 D5 verbatim).
// NOTE: assumes nblk=(N+255)/256 <= 256 (N <= 65536; harness N=40000).

#define CIN    64
#define COUT   128
#define BEVH   512
#define BEVW   512
#define HW     (BEVH * BEVW)     // 2^18
#define NBINS  16
#define PTS_PER_WAVE  8

// ---------------- K1: zero head + deterministic per-block bucket
__global__ __launch_bounds__(256) void bev_sort(
    const int* __restrict__ coords,   // [N,4]
    const int* __restrict__ stride_p,
    int*       __restrict__ head,     // [ncells] -> zeroed here
    int*       __restrict__ blkhist,  // [nblk,16]
    int*       __restrict__ sorted,   // [16, nblk*256] block-segmented
    int n, int nblk, int scap, int ncells)
{
    __shared__ int hist[NBINS];
    const int tid = threadIdx.x;
    const int vb  = blockIdx.x;

    // zero head (2MB over nblk*256 threads, int4 grid-stride)
    {
        int4* h4 = (int4*)head;
        const int tot4 = ncells >> 2;
        const int zero_stride = nblk * 256;
        for (int i = vb * 256 + tid; i < tot4; i += zero_stride)
            h4[i] = make_int4(0, 0, 0, 0);
    }

    if (tid < NBINS) hist[tid] = 0;
    __syncthreads();

    const int i = vb * 256 + tid;
    int k = 0, rank = 0;
    if (i < n) {
        k = coords[i * 4 + 1] / stride_p[0];
        rank = atomicAdd(&hist[k], 1);        // LDS atomic: block-local rank
    }
    __syncthreads();
    if (i < n)
        sorted[k * scap + vb * 256 + rank] = i;
    if (tid < NBINS)
        blkhist[vb * NBINS + tid] = hist[tid];
}

// ---------------- K2: block = (bin, sort-block-pair); two blkhist loads,
//                  direct rank->segment mapping, LDS-kernel matmul, push
__global__ __launch_bounds__(256) void bev_point(
    const int*   __restrict__ coords,
    const float* __restrict__ feats,    // [N,64]
    const float* __restrict__ kern,     // [16,64,128]
    const int*   __restrict__ stride_p,
    const int*   __restrict__ blkhist,  // [nblk,16]
    const int*   __restrict__ sorted,   // [16, scap]
    float*       __restrict__ f,        // [N,128]
    int*         __restrict__ head,     // [ncells] zeroed; stores pt+1
    int*         __restrict__ nxt,      // [N]; 0 = end-of-chain
    int n, int nblk, int scap, int ngrp)
{
    __shared__ float lk[CIN * COUT];    // 32 KB: kern[bin]

    const int tid = threadIdx.x;
    const int bin = blockIdx.x / ngrp;        // block-uniform
    const int grp = blockIdx.x - bin * ngrp;
    const int vb0 = grp * 2;
    const int vb1 = vb0 + 1;
    const int c0  = blkhist[vb0 * NBINS + bin];
    const int c1  = (vb1 < nblk) ? blkhist[vb1 * NBINS + bin] : 0;
    const int c   = c0 + c1;                  // ~32 avg points for this block
    if (c == 0) return;                       // uniform, pre-barrier: ok

    // stage kern[bin] -> LDS (256 thr x 8 float4)
    {
        const float4* src = (const float4*)(kern + (size_t)bin * CIN * COUT);
        float4* dst = (float4*)lk;
#pragma unroll
        for (int j = 0; j < 8; ++j)
            dst[j * 256 + tid] = src[j * 256 + tid];
    }
    __syncthreads();                          // no barrier after this point

    const int wave = tid >> 6;
    const int lane = tid & 63;
    const int sbase0 = bin * scap + vb0 * 256;
    const int sbase1 = bin * scap + vb1 * 256 - c0;  // pre-biased by c0
    const int stride = stride_p[0];

    // batch loop: wave w takes ranks [w*8, w*8+8) then strides by 32
    // (second iteration is rare: Poisson tail c > 32)
    for (int r0 = wave * PTS_PER_WAVE; r0 < c; r0 += 4 * PTS_PER_WAVE) {
        const int navail = c - r0;
        const int np = navail < PTS_PER_WAVE ? navail : PTS_PER_WAVE;

        int pts[PTS_PER_WAVE];
#pragma unroll
        for (int p = 0; p < PTS_PER_WAVE; ++p) {
            const int rr = (p < np) ? (r0 + p) : r0;   // pad tail (discarded)
            const int idx = (rr < c0) ? (sbase0 + rr) : (sbase1 + rr);
            pts[p] = __builtin_amdgcn_readfirstlane(sorted[idx]);
        }

        float ax[PTS_PER_WAVE], ay[PTS_PER_WAVE];
#pragma unroll
        for (int p = 0; p < PTS_PER_WAVE; ++p) { ax[p] = 0.f; ay[p] = 0.f; }

#pragma unroll
        for (int cc = 0; cc < CIN; ++cc) {
            const float2 kv = *(const float2*)&lk[cc * COUT + 2 * lane];
#pragma unroll
            for (int p = 0; p < PTS_PER_WAVE; ++p) {
                const float fv = feats[(size_t)pts[p] * CIN + cc];  // s_load
                ax[p] = fmaf(fv, kv.x, ax[p]);
                ay[p] = fmaf(fv, kv.y, ay[p]);
            }
        }

#pragma unroll
        for (int p = 0; p < PTS_PER_WAVE; ++p) {
            if (p < np)
                *(float2*)(f + (size_t)pts[p] * COUT + 2 * lane) =
                    make_float2(ax[p], ay[p]);
        }

        if (lane == 0) {
            for (int p = 0; p < np; ++p) {
                const int pt = pts[p];
                const int cx = coords[pt * 4 + 0];
                const int cz = coords[pt * 4 + 2];
                const int cb = coords[pt * 4 + 3];
                const int cell = (cb << 18) + ((cx / stride) << 9) + (cz / stride);
                const int old = atomicExch(&head[cell], pt + 1); // lock-free push
                nxt[pt] = old;                                   // 0 = end
            }
        }
    }
}

// ----------------- K3: R11 D4 verbatim — owner folds chain in-place into f
__global__ __launch_bounds__(256) void bev_accum(
    const int* __restrict__ coords,
    const int* __restrict__ stride_p,
    float*     __restrict__ f,          // [N,128] (in-place)
    const int* __restrict__ head,
    const int* __restrict__ nxt,
    int n)
{
    const int wave = threadIdx.x >> 6;
    const int lane = threadIdx.x & 63;
    int pt = blockIdx.x * 4 + wave;
    if (pt >= n) return;
    pt = __builtin_amdgcn_readfirstlane(pt);

    const int nx0 = __builtin_amdgcn_readfirstlane(nxt[pt]);
    if (nx0 == 0) return;                       // singleton or tail: nothing to fold

    const int stride = stride_p[0];
    const int cx = coords[pt * 4 + 0];
    const int cz = coords[pt * 4 + 2];
    const int cb = coords[pt * 4 + 3];
    const int cell = (cb << 18) + ((cx / stride) << 9) + (cz / stride);
    if (__builtin_amdgcn_readfirstlane(head[cell]) != pt + 1) return;  // owner only

    float2 acc = *(const float2*)(f + (size_t)pt * COUT + 2 * lane);
    int p = nx0;
    while (p) {                                 // disjoint chains: no hazards
        const float2 v = *(const float2*)(f + (size_t)(p - 1) * COUT + 2 * lane);
        acc.x += v.x; acc.y += v.y;
        p = __builtin_amdgcn_readfirstlane(nxt[p - 1]);
    }
    *(float2*)(f + (size_t)pt * COUT + 2 * lane) = acc;
}

// ------------- K4: R11 D5 verbatim — branch-free wave-per-row dense output
__global__ __launch_bounds__(256) void bev_dense_row(
    const float* __restrict__ f,        // [N,128] (owner rows hold cell sums)
    const int*   __restrict__ head,     // [ncells], pt+1 or 0
    float*       __restrict__ out,      // [B,128,512,512]
    int nrows)                          // B*COUT*BEVH
{
    const int wave = threadIdx.x >> 6;
    const int lane = threadIdx.x & 63;
    const int row = blockIdx.x * 4 + wave;      // row = (b<<16)|(o<<9)|x
    if (row >= nrows) return;

    const int x = row & 511;
    const int o = (row >> 9) & 127;             // wave-uniform
    const int b = row >> 16;                    // wave-uniform
    const int* hrow = head + (b << 18) + (x << 9);   // 2KB contiguous head row
    float* const orow = out + (size_t)row * 512;

#pragma unroll
    for (int h = 0; h < 2; ++h) {
        const int z = h * 256 + lane * 4;
        const int4 h4 = *(const int4*)(hrow + z);    // coalesced 1KB/wave
        float4 v = make_float4(0.f, 0.f, 0.f, 0.f);
        if (h4.x) v.x = f[(size_t)(h4.x - 1) * COUT + o];   // one scattered
        if (h4.y) v.y = f[(size_t)(h4.y - 1) * COUT + o];   // load level,
        if (h4.z) v.z = f[(size_t)(h4.z - 1) * COUT + o];   // branch-free
        if (h4.w) v.w = f[(size_t)(h4.w - 1) * COUT + o];
        *(float4*)(orow + z) = v;                    // coalesced 1KB/wave store
    }
}

// ------------------------------------------------------------------- launch
extern "C" void kernel_launch(void* const* d_in, const int* in_sizes, int n_in,
                              void* d_out, int out_size, void* d_ws, size_t ws_size,
                              hipStream_t stream) {
    const int*   coords   = (const int*)d_in[0];
    const float* feats    = (const float*)d_in[1];
    const float* kern     = (const float*)d_in[2];
    const int*   stride_p = (const int*)d_in[3];
    float* out = (float*)d_out;

    const int n      = in_sizes[0] / 4;      // coords is [N,4]
    const int ncells = out_size / COUT;      // B*H*W = 524288
    const int nblk   = (n + 255) / 256;      // sort blocks (157; must be <=256)
    const int scap   = nblk * 256;           // per-bin segment capacity
    const int ngrp   = (nblk + 1) / 2;       // sort-block pairs (79)

    // Workspace: f | head | nxt | blkhist | sorted   (nothing needs memset)
    size_t off = 0;
    float* f      = (float*)((char*)d_ws + off); off += (size_t)n * COUT * sizeof(float);
    int* head     = (int*)((char*)d_ws + off);   off += (size_t)ncells * sizeof(int);
    int* nxt      = (int*)((char*)d_ws + off);   off += (size_t)n * sizeof(int);
    int* blkhist  = (int*)((char*)d_ws + off);   off += (size_t)nblk * NBINS * sizeof(int);
    int* sorted   = (int*)((char*)d_ws + off);   off += (size_t)NBINS * scap * sizeof(int);

    // K1: zero head + bucket (head zeroing ordered before K2 by dispatch order)
    bev_sort<<<nblk, 256, 0, stream>>>(coords, stride_p, head, blkhist, sorted,
                                       n, nblk, scap, ncells);

    // K2: (bin, sort-block-pair) grid — 16 x 79 = 1264 working blocks
    bev_point<<<NBINS * ngrp, 256, 0, stream>>>(coords, feats, kern, stride_p,
                                                blkhist, sorted, f, head, nxt,
                                                n, nblk, scap, ngrp);

    // K3: owner folds collision chains (R11 D4)
    bev_accum<<<(n + 3) / 4, 256, 0, stream>>>(coords, stride_p, f, head, nxt, n);

    // K4: branch-free dense output (R11 D5)
    const int nrows = out_size / 512;        // B*COUT*BEVH = 131072
    bev_dense_row<<<nrows / 4, 256, 0, stream>>>(f, head, out, nrows);
}

// Round 8
// 346.971 us; speedup vs baseline: 1.0538x; 1.0538x over previous
//
#include <hip/hip_runtime.h>

// ToDenseBEVConvolution R19 == R11 verbatim (best measured: 350.5/351.3 us).
// Session ledger (R12-R18): every structural deviation measured worse —
//  R12 1-node cooperative: 1528 (grid capped at 1024 blocks -> TLP collapse)
//  R13/R14 blkhist+prologue w/ LDS-atomic storm: 451/445 (same-address
//          lockstep atomicAdd x2512/block — the one real finding, -87us fix)
//  R15 4-node atomic-free prologue: 357.8
//  R16 walk-in-dense: 365.4 (chain-walk costs ~18us > boundary ~saved)
//  R17 o16-dense: 365.1 (f/head already cache-resident; dense at store floor)
//  R18 pair-indexed point: 365.6 (prologue was never the cost)
// Conclusion: 5-node R11 structure is the local optimum; remaining headroom
// (<20us across dense/point interiors) is below the harness noise floor
// (~±8us, fills drift 170-187us) and invisible to top-5 counters.
//  D1 memset:   head+gcnt zeroed in ONE call (head uses pt+1 encoding, 0=empty).
//  D2 bev_sort: bucket point indices by k-bin.
//  D3 bev_point: binned matmul, kern[k] in LDS; f[N,128]; head=pt+1 (atomicExch),
//               nxt[pt]=old (0 = end).
//  D4 bev_accum: owner (head[cell]==pt+1) with a real collision chain
//               (nxt!=0) sums chain IN-PLACE into its own f row. Chains are
//               disjoint -> no cross-owner hazard. ~96% of cells are
//               singletons -> skip; only ~1.4k waves do work.
//  D5 bev_dense_row: wave per 2KB output row; lane loads head[z..z+3] as ONE
//               coalesced int4; occupied -> one scattered f load (2-deep
//               chain, level-1 coalesced); 1KB coalesced float4 stores.

#define CIN    64
#define COUT   128
#define BEVH   512
#define BEVW   512
#define HW     (BEVH * BEVW)     // 2^18
#define NBINS  16
#define PTS_PER_WAVE  8
#define PTS_PER_BLOCK 32

// ---------------------------------------------------------------- D2: bucket
__global__ __launch_bounds__(256) void bev_sort(
    const int* __restrict__ coords,   // [N,4]
    const int* __restrict__ stride_p,
    int*       __restrict__ gcnt,     // [16] init 0
    int*       __restrict__ sorted,   // [16*N]
    int n)
{
    __shared__ int hist[NBINS];
    __shared__ int base[NBINS];
    const int tid = threadIdx.x;
    if (tid < NBINS) hist[tid] = 0;
    __syncthreads();

    const int i = blockIdx.x * 256 + tid;
    int k = 0, rank = 0;
    if (i < n) {
        k = coords[i * 4 + 1] / stride_p[0];
        rank = atomicAdd(&hist[k], 1);        // LDS atomic: block-local rank
    }
    __syncthreads();
    if (tid < NBINS)
        base[tid] = hist[tid] ? atomicAdd(&gcnt[tid], hist[tid]) : 0;
    __syncthreads();
    if (i < n)
        sorted[k * n + base[k] + rank] = i;
}

// ------------------------------------------------------- D3: per-point matmul
__global__ __launch_bounds__(256) void bev_point(
    const int*   __restrict__ coords,
    const float* __restrict__ feats,    // [N,64]
    const float* __restrict__ kern,     // [16,64,128]
    const int*   __restrict__ stride_p,
    const int*   __restrict__ gcnt,     // [16]
    const int*   __restrict__ sorted,   // [16*N]
    float*       __restrict__ f,        // [N,128]
    int*         __restrict__ head,     // [ncells] init 0; stores pt+1
    int*         __restrict__ nxt,      // [N]; 0 = end-of-chain
    int n, int chunks_per_bin)
{
    __shared__ float lk[CIN * COUT];    // 32 KB: kern[bin]

    const int bin   = blockIdx.x / chunks_per_bin;
    const int chunk = blockIdx.x % chunks_per_bin;
    const int cnt   = gcnt[bin];
    const int r0blk = chunk * PTS_PER_BLOCK;
    if (r0blk >= cnt) return;                 // uniform across block, pre-barrier: ok

    // stage kern[bin] -> LDS (256 thr x 8 float4)
    {
        const float4* src = (const float4*)(kern + (size_t)bin * CIN * COUT);
        float4* dst = (float4*)lk;
#pragma unroll
        for (int j = 0; j < 8; ++j)
            dst[j * 256 + threadIdx.x] = src[j * 256 + threadIdx.x];
    }
    __syncthreads();

    const int wave = threadIdx.x >> 6;
    const int lane = threadIdx.x & 63;
    const int r0 = r0blk + wave * PTS_PER_WAVE;
    const int navail = cnt - r0;
    if (navail <= 0) return;                  // no barrier after this point
    const int np = navail < PTS_PER_WAVE ? navail : PTS_PER_WAVE;

    int pts[PTS_PER_WAVE];
#pragma unroll
    for (int p = 0; p < PTS_PER_WAVE; ++p) {
        const int rr = (p < np) ? (r0 + p) : r0;   // pad tail with p0 (discarded)
        pts[p] = __builtin_amdgcn_readfirstlane(sorted[bin * n + rr]);
    }

    float ax[PTS_PER_WAVE], ay[PTS_PER_WAVE];
#pragma unroll
    for (int p = 0; p < PTS_PER_WAVE; ++p) { ax[p] = 0.f; ay[p] = 0.f; }

#pragma unroll
    for (int c = 0; c < CIN; ++c) {
        const float2 kv = *(const float2*)&lk[c * COUT + 2 * lane];
#pragma unroll
        for (int p = 0; p < PTS_PER_WAVE; ++p) {
            const float fv = feats[(size_t)pts[p] * CIN + c];  // wave-uniform -> s_load
            ax[p] = fmaf(fv, kv.x, ax[p]);
            ay[p] = fmaf(fv, kv.y, ay[p]);
        }
    }

#pragma unroll
    for (int p = 0; p < PTS_PER_WAVE; ++p) {
        if (p < np)
            *(float2*)(f + (size_t)pts[p] * COUT + 2 * lane) = make_float2(ax[p], ay[p]);
    }

    if (lane == 0) {
        const int stride = stride_p[0];
        for (int p = 0; p < np; ++p) {
            const int pt = pts[p];
            const int cx = coords[pt * 4 + 0];
            const int cz = coords[pt * 4 + 2];
            const int cb = coords[pt * 4 + 3];
            const int cell = (cb << 18) + ((cx / stride) << 9) + (cz / stride);
            const int old = atomicExch(&head[cell], pt + 1);   // spread: cheap
            nxt[pt] = old;                                     // 0 = end
        }
    }
}

// ----------------- D4: owner folds collision chain in-place into its f row
__global__ __launch_bounds__(256) void bev_accum(
    const int* __restrict__ coords,
    const int* __restrict__ stride_p,
    float*     __restrict__ f,          // [N,128] (in-place)
    const int* __restrict__ head,
    const int* __restrict__ nxt,
    int n)
{
    const int wave = threadIdx.x >> 6;
    const int lane = threadIdx.x & 63;
    int pt = blockIdx.x * 4 + wave;
    if (pt >= n) return;
    pt = __builtin_amdgcn_readfirstlane(pt);

    const int nx0 = __builtin_amdgcn_readfirstlane(nxt[pt]);
    if (nx0 == 0) return;                       // singleton or tail: nothing to fold

    const int stride = stride_p[0];
    const int cx = coords[pt * 4 + 0];
    const int cz = coords[pt * 4 + 2];
    const int cb = coords[pt * 4 + 3];
    const int cell = (cb << 18) + ((cx / stride) << 9) + (cz / stride);
    if (__builtin_amdgcn_readfirstlane(head[cell]) != pt + 1) return;  // owner only

    float2 acc = *(const float2*)(f + (size_t)pt * COUT + 2 * lane);
    int p = nx0;
    while (p) {                                 // disjoint chains: no hazards
        const float2 v = *(const float2*)(f + (size_t)(p - 1) * COUT + 2 * lane);
        acc.x += v.x; acc.y += v.y;
        p = __builtin_amdgcn_readfirstlane(nxt[p - 1]);
    }
    *(float2*)(f + (size_t)pt * COUT + 2 * lane) = acc;
}

// ------------------- D5: wave-per-row dense output (int4 head, plain stores)
__global__ __launch_bounds__(256) void bev_dense_row(
    const float* __restrict__ f,        // [N,128] (owner rows hold cell sums)
    const int*   __restrict__ head,     // [ncells], pt+1 or 0
    float*       __restrict__ out,      // [B,128,512,512]
    int nrows)                          // B*COUT*BEVH
{
    const int wave = threadIdx.x >> 6;
    const int lane = threadIdx.x & 63;
    const int row = blockIdx.x * 4 + wave;      // row = (b<<16)|(o<<9)|x
    if (row >= nrows) return;

    const int x = row & 511;
    const int o = (row >> 9) & 127;             // wave-uniform
    const int b = row >> 16;                    // wave-uniform
    const int* hrow = head + (b << 18) + (x << 9);   // 2KB contiguous head row
    float* const orow = out + (size_t)row * 512;

#pragma unroll
    for (int h = 0; h < 2; ++h) {
        const int z = h * 256 + lane * 4;
        const int4 h4 = *(const int4*)(hrow + z);    // coalesced 1KB/wave
        float4 v = make_float4(0.f, 0.f, 0.f, 0.f);
        if (h4.x) v.x = f[(size_t)(h4.x - 1) * COUT + o];   // 2-deep chain,
        if (h4.y) v.y = f[(size_t)(h4.y - 1) * COUT + o];   // one scattered
        if (h4.z) v.z = f[(size_t)(h4.z - 1) * COUT + o];   // load level
        if (h4.w) v.w = f[(size_t)(h4.w - 1) * COUT + o];
        *(float4*)(orow + z) = v;                    // coalesced 1KB/wave store
    }
}

// ------------------------------------------------------------------- launch
extern "C" void kernel_launch(void* const* d_in, const int* in_sizes, int n_in,
                              void* d_out, int out_size, void* d_ws, size_t ws_size,
                              hipStream_t stream) {
    const int*   coords   = (const int*)d_in[0];
    const float* feats    = (const float*)d_in[1];
    const float* kern     = (const float*)d_in[2];
    const int*   stride_p = (const int*)d_in[3];
    float* out = (float*)d_out;

    const int n      = in_sizes[0] / 4;      // coords is [N,4]
    const int ncells = out_size / COUT;      // B*H*W = 524288

    // Workspace: f | head | gcnt | nxt | sorted   (head+gcnt contiguous -> 1 memset)
    size_t off = 0;
    float* f = (float*)((char*)d_ws + off);          off += (size_t)n * COUT * sizeof(float);
    int* head = (int*)((char*)d_ws + off);           off += (size_t)ncells * sizeof(int);
    int* gcnt = (int*)((char*)d_ws + off);           off += NBINS * sizeof(int);
    int* nxt  = (int*)((char*)d_ws + off);           off += (size_t)n * sizeof(int);
    int* sorted = (int*)((char*)d_ws + off);         off += (size_t)NBINS * n * sizeof(int);

    // D1: ws re-poisoned to 0xAA before every timed launch -> one zeroing memset
    (void)hipMemsetAsync(head, 0,
                         (size_t)ncells * sizeof(int) + NBINS * sizeof(int), stream);

    // D2
    bev_sort<<<(n + 255) / 256, 256, 0, stream>>>(coords, stride_p, gcnt, sorted, n);

    // D3
    const int chunks_per_bin = (n + PTS_PER_BLOCK - 1) / PTS_PER_BLOCK;
    bev_point<<<NBINS * chunks_per_bin, 256, 0, stream>>>(
        coords, feats, kern, stride_p, gcnt, sorted, f, head, nxt,
        n, chunks_per_bin);

    // D4
    bev_accum<<<(n + 3) / 4, 256, 0, stream>>>(coords, stride_p, f, head, nxt, n);

    // D5
    const int nrows = out_size / 512;        // B*COUT*BEVH = 131072
    bev_dense_row<<<nrows / 4, 256, 0, stream>>>(f, head, out, nrows);
}